// Round 2
// baseline (249.341 us; speedup 1.0000x reference)
//
#include <hip/hip_runtime.h>
#include <cstdio>

// ---------------------------------------------------------------------------
// MemoryEfficientRGBDecoderStem — algebraic reduction + fused bf16 MFMA:
//   GEMM1 K collapses 1156 -> 136 (pad 144): gestalt is spatially constant
//   (per-batch Wg), cos embeddings are separable in h/w.
//   A-tile built on the fly in LDS (no big workspace). B1/W2 pre-packed into
//   frag-contiguous layouts so every MFMA operand load is a 1KB wave read.
// ---------------------------------------------------------------------------

#define NFREQ 16
#define BB 16
#define G 256
#define KIN 1156
#define K1 144

typedef unsigned short u16;
using bf16x8 = __bf16 __attribute__((ext_vector_type(8)));
using f32x16 = float __attribute__((ext_vector_type(16)));
using f32x4  = float __attribute__((ext_vector_type(4)));

__device__ __forceinline__ u16 f2bf(float f) {
  unsigned u = __float_as_uint(f);
  u += 0x7fffu + ((u >> 16) & 1u);
  return (u16)(u >> 16);
}
__device__ __forceinline__ unsigned pk2(float a, float b) {
  return (unsigned)f2bf(a) | ((unsigned)f2bf(b) << 16);
}

// --------------------------- prologue kernels ------------------------------

// cos tables: cosx[b][f][w], cosy[b][f][h] — exact fp32 op-order of reference
__global__ void k_tables(const float* __restrict__ pos,
                         float* __restrict__ cosx, float* __restrict__ cosy) {
  int idx = blockIdx.x * 256 + threadIdx.x;   // 0..65535
  int table = idx >> 15;
  int rem = idx & 32767;
  int b = rem >> 11;
  int f = (rem >> 7) & 15;
  int c = rem & 127;
  float p0 = pos[b * 4 + 0];
  float p1 = pos[b * 4 + 1];
  float p3 = pos[b * 4 + 3];
  float x = fminf(fmaxf(p0, -1.f), 1.f);
  float y = fminf(fmaxf(p1, -1.f), 1.f);
  float stdv = 0.1f / fminf(fmaxf(p3, 0.0078125f), 0.5f);  // min_std = 1/128
  const float half_pi = 1.57079632679489661923f;
  float g = ((float)c / 127.0f) * 2.0f - 1.0f;
  float ng = (table == 0) ? ((g - x) * stdv) * half_pi      // std_x = std*(W/H)=std
                          : ((g - y) * stdv) * half_pi;
  float freq = (float)(1 << f);
  float val = cosf(ng * freq);
  if (table == 0) cosx[(b * NFREQ + f) * 128 + c] = val;
  else            cosy[(b * NFREQ + f) * 128 + c] = val;
}

// W2 (fp32 [256][1024]) -> frag-contiguous bf16 W2F:
// idx = ((((nc*4+ks2)*2+wn)*4+ct)*64 + lane)*8 + i
//   n2 = wn*128 + ct*32 + (lane&31), k2 = nc*64 + ks2*16 + (lane>>5)*8 + i
__global__ void k_w2f(const float* __restrict__ w2, u16* __restrict__ W2F) {
  int e = blockIdx.x * 256 + threadIdx.x;     // 0..262143
  int i   = e & 7;
  int lane = (e >> 3) & 63;
  int ct  = (e >> 9) & 3;
  int wnn = (e >> 11) & 1;
  int ks2 = (e >> 12) & 3;
  int nc  = e >> 14;
  int l31 = lane & 31, lhi = lane >> 5;
  int n2 = wnn * 128 + ct * 32 + l31;
  int k2 = nc * 64 + ks2 * 16 + lhi * 8 + i;
  W2F[e] = f2bf(w2[n2 * 1024 + k2]);
}

// B1F: per-batch reduced W1 in frag-contiguous bf16 layout.
// k layout [0,144): 64 x-emb, 64 y-emb, 4 Wg(mask), 4 Wd(depth), 8 pad.
// idx = (((((b*16+nc)*2+wn)*9+ks)*64) + lhi*32 + l31)*8 + i
//   n = nc*64 + wn*32 + l31, k = ks*16 + lhi*8 + i
__global__ void k_b1f(const float* __restrict__ w1, const float* __restrict__ gestalt,
                      u16* __restrict__ B1F) {
  __shared__ float w1row[KIN];
  __shared__ float gest[BB * G];
  __shared__ float wg[64];
  const int n = blockIdx.x;
  const int t = threadIdx.x;
  for (int i = t; i < KIN; i += 256) w1row[i] = w1[(size_t)n * KIN + i];
  for (int i = t; i < BB * G; i += 256) gest[i] = gestalt[i];
  __syncthreads();
  if (t < 64) {
    int bb = t >> 2, j = t & 3;
    float acc = 0.f;
    for (int c = 0; c < G; ++c) acc += gest[bb * G + c] * w1row[4 * c + j];
    wg[t] = acc;
  }
  __syncthreads();
  const int nc = n >> 6, wnn = (n >> 5) & 1, l31n = n & 31;
  for (int e = t; e < BB * K1; e += 256) {
    int bb = e / K1, k = e - bb * K1;
    float v;
    if (k < 64)       v = w1row[1024 + 8 * (k >> 2) + (k & 3)];
    else if (k < 128) { int kk = k - 64; v = w1row[1024 + 8 * (kk >> 2) + 4 + (kk & 3)]; }
    else if (k < 132) v = wg[bb * 4 + (k - 128)];
    else if (k < 136) v = w1row[1152 + (k - 132)];
    else              v = 0.f;
    int ks = k >> 4, lhi2 = (k >> 3) & 1, ii = k & 7;
    size_t idx = (((((size_t)bb * 16 + nc) * 2 + wnn) * 9 + ks) * 64 + lhi2 * 32 + l31n) * 8 + ii;
    B1F[idx] = f2bf(v);
  }
}

// ------------------------------ main kernel --------------------------------
// 512 blocks x 256 thr (4 waves: wr=row-half, wn=hidden/n2-half), 128-row tile.
// lA built on the fly; rt=0 A-col frags register-cached; af/wf are contiguous
// 1KB wave loads from L2-resident B1F/W2F; S round-trips through lS per nc.
__global__ __launch_bounds__(256, 2) void k_main(
    const u16* __restrict__ B1F, const u16* __restrict__ W2F,
    const float* __restrict__ mask, const float* __restrict__ depth,
    const float* __restrict__ cosx, const float* __restrict__ cosy,
    const float* __restrict__ bias1, const float* __restrict__ bias2,
    float* __restrict__ out)
{
  __shared__ __align__(16) u16 lA[128 * 152];   // 38912 B
  __shared__ __align__(16) u16 lS[128 * 72];    // 18432 B (prologue: float staging)
  float* stg = (float*)lS;

  const int tid = threadIdx.x;
  const int wid = tid >> 6;
  const int lane = tid & 63;
  const int l31 = lane & 31;
  const int lhi = lane >> 5;
  const int wr = wid >> 1;
  const int wn = wid & 1;
  const int r0 = blockIdx.x * 128;
  const int b = r0 >> 12;
  const int oy0 = (r0 >> 6) & 63;   // even

  // ---- stage tables: cosx[b] (2048f), cosy[b] 4 h-rows (64f), mask/depth 4 rows ----
  {
    const float4* cx4 = (const float4*)(cosx + (size_t)b * 2048);
    ((float4*)stg)[tid]       = cx4[tid];
    ((float4*)stg)[tid + 256] = cx4[tid + 256];
    if (tid < 64)
      stg[2048 + tid] = cosy[((size_t)b * 16 + (tid >> 2)) * 128 + 2 * oy0 + (tid & 3)];
    if (tid < 128) {
      ((float4*)(stg + 2112))[tid] = ((const float4*)(mask  + ((size_t)b * 128 + 2 * oy0) * 128))[tid];
      ((float4*)(stg + 2624))[tid] = ((const float4*)(depth + ((size_t)b * 128 + 2 * oy0) * 128))[tid];
    }
  }
  __syncthreads();

  // ---- build lA[row][k] (stride 152) ----
  {
    const int rl = tid & 127;      // row in tile
    const int kh = tid >> 7;       // wave-uniform k-half: 0 -> k 0..71, 1 -> 72..143
    const int oyl = rl >> 6, ox = rl & 63;
    float m[4], dd[4];
#pragma unroll
    for (int j = 0; j < 4; ++j) {
      int sy = j >> 1, sx = j & 1;
      float mv = stg[2112 + (2 * oyl + sy) * 128 + 2 * ox + sx];
      m[j] = mv;
      dd[j] = stg[2624 + (2 * oyl + sy) * 128 + 2 * ox + sx] * mv;
    }
    unsigned* dst = (unsigned*)(lA + rl * 152);
    if (kh == 0) {
#pragma unroll
      for (int kk = 0; kk < 18; ++kk) {
        const int k0 = kk * 4;
        float v0, v1, v2, v3;
        if (k0 < 64) {          // x-emb: f = k0>>2, sx = j&1
          const int f = k0 >> 2;
          float ca = stg[f * 128 + 2 * ox], cb = stg[f * 128 + 2 * ox + 1];
          v0 = m[0] * ca; v1 = m[1] * cb; v2 = m[2] * ca; v3 = m[3] * cb;
        } else {                // y-emb f=0,1: sy = j>>1
          const int f = (k0 - 64) >> 2;
          float ca = stg[2048 + f * 4 + 2 * oyl], cb = stg[2048 + f * 4 + 2 * oyl + 1];
          v0 = m[0] * ca; v1 = m[1] * ca; v2 = m[2] * cb; v3 = m[3] * cb;
        }
        dst[k0 / 2]     = pk2(v0, v1);
        dst[k0 / 2 + 1] = pk2(v2, v3);
      }
    } else {
#pragma unroll
      for (int kk = 0; kk < 18; ++kk) {
        const int k0 = 72 + kk * 4;
        float v0, v1, v2, v3;
        if (k0 < 128) {         // y-emb f=2..15
          const int f = (k0 - 64) >> 2;
          float ca = stg[2048 + f * 4 + 2 * oyl], cb = stg[2048 + f * 4 + 2 * oyl + 1];
          v0 = m[0] * ca; v1 = m[1] * ca; v2 = m[2] * cb; v3 = m[3] * cb;
        } else if (k0 == 128) { v0 = m[0]; v1 = m[1]; v2 = m[2]; v3 = m[3]; }
        else if (k0 == 132)   { v0 = dd[0]; v1 = dd[1]; v2 = dd[2]; v3 = dd[3]; }
        else                  { v0 = v1 = v2 = v3 = 0.f; }
        dst[k0 / 2]     = pk2(v0, v1);
        dst[k0 / 2 + 1] = pk2(v2, v3);
      }
    }
  }
  __syncthreads();

  // ---- preload rt=0 A-tile B-frags into registers ----
  bf16x8 bfr[9];
  const int rowA0 = (wr * 64 + l31) * 152 + lhi * 8;
  const int rowA1 = rowA0 + 32 * 152;
#pragma unroll
  for (int ks = 0; ks < 9; ++ks) bfr[ks] = *(const bf16x8*)&lA[rowA0 + ks * 16];

  f32x16 acc2[2][4];
#pragma unroll
  for (int a = 0; a < 2; ++a)
#pragma unroll
    for (int c = 0; c < 4; ++c)
#pragma unroll
      for (int i = 0; i < 16; ++i) acc2[a][c][i] = 0.f;

  const u16* b1p  = B1F + (size_t)b * 16 * 9216 + (size_t)wn * 4608 + (size_t)lane * 8;
  const u16* w2p0 = W2F + (size_t)wn * 2048 + (size_t)lane * 8;

  for (int nc = 0; nc < 16; ++nc) {
    f32x16 acc1[2];
#pragma unroll
    for (int a = 0; a < 2; ++a)
#pragma unroll
      for (int i = 0; i < 16; ++i) acc1[a][i] = 0.f;

    const u16* ap = b1p + nc * 9216;
#pragma unroll
    for (int ks = 0; ks < 9; ++ks) {
      bf16x8 af = *(const bf16x8*)(ap + ks * 512);   // contiguous 1KB wave load
      acc1[0] = __builtin_amdgcn_mfma_f32_32x32x16_bf16(af, bfr[ks], acc1[0], 0, 0, 0);
      acc1[1] = __builtin_amdgcn_mfma_f32_32x32x16_bf16(af, *(const bf16x8*)&lA[rowA1 + ks * 16], acc1[1], 0, 0, 0);
    }

    // bias1 + SiLU -> lS[r][n_local]
    const int n0 = nc * 64;
#pragma unroll
    for (int rt = 0; rt < 2; ++rt) {
      const int r = wr * 64 + rt * 32 + l31;
#pragma unroll
      for (int j = 0; j < 4; ++j) {
        const int nl = wn * 32 + 8 * j + 4 * lhi;
        f32x4 bs = *(const f32x4*)(bias1 + n0 + nl);
        float h0 = acc1[rt][4 * j + 0] + bs[0];
        float h1 = acc1[rt][4 * j + 1] + bs[1];
        float h2 = acc1[rt][4 * j + 2] + bs[2];
        float h3 = acc1[rt][4 * j + 3] + bs[3];
        float s0 = h0 / (1.f + __expf(-h0));
        float s1 = h1 / (1.f + __expf(-h1));
        float s2 = h2 / (1.f + __expf(-h2));
        float s3 = h3 / (1.f + __expf(-h3));
        uint2 pv;
        pv.x = pk2(s0, s1);
        pv.y = pk2(s2, s3);
        *(uint2*)(&lS[r * 72 + nl]) = pv;
      }
    }
    __syncthreads();

    // GEMM2: out[r][n2] += S[r][k] * W2[n2][k]
#pragma unroll
    for (int ks2 = 0; ks2 < 4; ++ks2) {
      bf16x8 sa0 = *(const bf16x8*)&lS[(wr * 64 + l31) * 72 + ks2 * 16 + lhi * 8];
      bf16x8 sa1 = *(const bf16x8*)&lS[(wr * 64 + 32 + l31) * 72 + ks2 * 16 + lhi * 8];
      const u16* wp = w2p0 + nc * 16384 + ks2 * 4096;
#pragma unroll
      for (int ct = 0; ct < 4; ++ct) {
        bf16x8 wf = *(const bf16x8*)(wp + ct * 512); // contiguous 1KB wave load
        acc2[0][ct] = __builtin_amdgcn_mfma_f32_32x32x16_bf16(sa0, wf, acc2[0][ct], 0, 0, 0);
        acc2[1][ct] = __builtin_amdgcn_mfma_f32_32x32x16_bf16(sa1, wf, acc2[1][ct], 0, 0, 0);
      }
    }
    __syncthreads();
  }

  // ---- epilogue: out[b][n2][oy][ox] = acc2 + bias2, float4 along ox ----
#pragma unroll
  for (int ct = 0; ct < 4; ++ct) {
    const int n2 = wn * 128 + ct * 32 + l31;
    const float b2 = bias2[n2];
    float* ob = out + ((size_t)b * 256 + n2) * 4096;
#pragma unroll
    for (int rt = 0; rt < 2; ++rt) {
#pragma unroll
      for (int j = 0; j < 4; ++j) {
        const int rl = wr * 64 + rt * 32 + 8 * j + 4 * lhi;
        const int oy = oy0 + (rl >> 6);
        const int ox = rl & 63;
        f32x4 v;
        v[0] = acc2[rt][ct][4 * j + 0] + b2;
        v[1] = acc2[rt][ct][4 * j + 1] + b2;
        v[2] = acc2[rt][ct][4 * j + 2] + b2;
        v[3] = acc2[rt][ct][4 * j + 3] + b2;
        *(f32x4*)(ob + oy * 64 + ox) = v;
      }
    }
  }
}

// ------------------------------- launcher ----------------------------------

extern "C" void kernel_launch(void* const* d_in, const int* in_sizes, int n_in,
                              void* d_out, int out_size, void* d_ws, size_t ws_size,
                              hipStream_t stream) {
  const float* pos     = (const float*)d_in[0];
  const float* gestalt = (const float*)d_in[1];
  const float* mask    = (const float*)d_in[2];
  const float* depth   = (const float*)d_in[3];
  const float* w1      = (const float*)d_in[4];
  const float* bias1   = (const float*)d_in[5];
  const float* w2      = (const float*)d_in[6];
  const float* bias2   = (const float*)d_in[7];
  float* out = (float*)d_out;

  // workspace: cosx 128KB | cosy 128KB | B1F 4.5MB | W2F 512KB = 5,505,024 B
  const size_t NEED = 131072u + 131072u + 4718592u + 524288u;
  if (ws_size < NEED) {
    fprintf(stderr, "[kernel] ws_size=%zu < needed %zu — skipping launches\n",
            ws_size, NEED);
    return;
  }
  char* ws = (char*)d_ws;
  float* cosx = (float*)(ws);
  float* cosy = (float*)(ws + 131072);
  u16*   B1F  = (u16*)(ws + 262144);
  u16*   W2F  = (u16*)(ws + 262144 + 4718592);

  k_tables<<<256, 256, 0, stream>>>(pos, cosx, cosy);
  k_w2f<<<1024, 256, 0, stream>>>(w2, W2F);
  k_b1f<<<1024, 256, 0, stream>>>(w1, gestalt, B1F);
  k_main<<<512, 256, 0, stream>>>(B1F, W2F, mask, depth, cosx, cosy, bias1, bias2, out);
}